// Round 1
// baseline (156.641 us; speedup 1.0000x reference)
//
#include <hip/hip_runtime.h>
#include <math.h>

// ---------------------------------------------------------------------------
// Kernel 1: per-camera precompute. 1000 cameras -> cams[c*12] = {R[9], t[3]}
// ---------------------------------------------------------------------------
__global__ void cam_precompute(const float* __restrict__ params,
                               float* __restrict__ cams, int size) {
    int c = blockIdx.x * blockDim.x + threadIdx.x;
    if (c >= size) return;
    float a  = params[6 * c + 0];
    float b  = params[6 * c + 1];
    float cc = params[6 * c + 2];
    float t2 = a * a + b * b + cc * cc;
    float t  = sqrtf(t2);
    float sin_c, cos_c;
    if (t < 1e-8f) {
        sin_c = 1.0f;
        cos_c = 0.5f;
    } else {
        sin_c = sinf(t) / t;
        cos_c = (1.0f - cosf(t)) / t2;
    }
    float sa = sin_c * a, sb = sin_c * b, sc = sin_c * cc;
    float cab = cos_c * a * b, cac = cos_c * a * cc, cbc = cos_c * b * cc;

    float* o = cams + 12 * c;
    // R = I + sin_c*K + cos_c*K*K,  K = [[0,a,b],[-a,0,c],[-b,-c,0]]
    o[0] = 1.0f - cos_c * (a * a + b * b);
    o[1] =  sa - cbc;
    o[2] =  sb + cac;
    o[3] = -sa - cbc;
    o[4] = 1.0f - cos_c * (a * a + cc * cc);
    o[5] =  sc - cab;
    o[6] = -sb + cac;
    o[7] = -sc - cab;
    o[8] = 1.0f - cos_c * (b * b + cc * cc);
    o[9]  = params[6 * c + 3];
    o[10] = params[6 * c + 4];
    o[11] = params[6 * c + 5];
}

// ---------------------------------------------------------------------------
// Kernel 2: streaming transform. 4 points per thread, all float4 I/O.
// out layout (floats): [new_o: 3N][new_d: 3N][trans: 3N][R: 9N]
// ---------------------------------------------------------------------------
__launch_bounds__(256)
__global__ void cam_apply(const int* __restrict__ idx,
                          const float4* __restrict__ o4,
                          const float4* __restrict__ d4,
                          const float* __restrict__ cams,
                          float* __restrict__ out,
                          long long nq, long long N) {
    long long t = blockIdx.x * 256LL + threadIdx.x;
    if (t >= nq) return;
    long long base = 4LL * t;

    float ox[4], oy[4], oz[4], dx[4], dy[4], dz[4];
    int id[4];
    bool full = (base + 3 < N);

    if (full) {
        float4 A = o4[3 * t + 0], B = o4[3 * t + 1], C = o4[3 * t + 2];
        ox[0] = A.x; oy[0] = A.y; oz[0] = A.z;
        ox[1] = A.w; oy[1] = B.x; oz[1] = B.y;
        ox[2] = B.z; oy[2] = B.w; oz[2] = C.x;
        ox[3] = C.y; oy[3] = C.z; oz[3] = C.w;
        A = d4[3 * t + 0]; B = d4[3 * t + 1]; C = d4[3 * t + 2];
        dx[0] = A.x; dy[0] = A.y; dz[0] = A.z;
        dx[1] = A.w; dy[1] = B.x; dz[1] = B.y;
        dx[2] = B.z; dy[2] = B.w; dz[2] = C.x;
        dx[3] = C.y; dy[3] = C.z; dz[3] = C.w;
        int4 I4 = ((const int4*)idx)[t];
        id[0] = I4.x; id[1] = I4.y; id[2] = I4.z; id[3] = I4.w;
    } else {
        for (int k = 0; k < 4; ++k) {
            long long n = base + k;
            if (n < N) {
                ox[k] = ((const float*)o4)[3 * n + 0];
                oy[k] = ((const float*)o4)[3 * n + 1];
                oz[k] = ((const float*)o4)[3 * n + 2];
                dx[k] = ((const float*)d4)[3 * n + 0];
                dy[k] = ((const float*)d4)[3 * n + 1];
                dz[k] = ((const float*)d4)[3 * n + 2];
                id[k] = idx[n];
            } else {
                ox[k] = oy[k] = oz[k] = dx[k] = dy[k] = dz[k] = 0.0f;
                id[k] = 0;
            }
        }
    }

    float no[12], nd[12], tr[12], Rm[36];
#pragma unroll
    for (int k = 0; k < 4; ++k) {
        const float4* cam = (const float4*)(cams + 12 * id[k]);
        float4 c0 = cam[0], c1 = cam[1], c2 = cam[2];
        float r00 = c0.x, r01 = c0.y, r02 = c0.z;
        float r10 = c0.w, r11 = c1.x, r12 = c1.y;
        float r20 = c1.z, r21 = c1.w, r22 = c2.x;
        float tx = c2.y, ty = c2.z, tz = c2.w;

        no[3 * k + 0] = r00 * ox[k] + r01 * oy[k] + r02 * oz[k] + tx;
        no[3 * k + 1] = r10 * ox[k] + r11 * oy[k] + r12 * oz[k] + ty;
        no[3 * k + 2] = r20 * ox[k] + r21 * oy[k] + r22 * oz[k] + tz;

        nd[3 * k + 0] = r00 * dx[k] + r01 * dy[k] + r02 * dz[k];
        nd[3 * k + 1] = r10 * dx[k] + r11 * dy[k] + r12 * dz[k];
        nd[3 * k + 2] = r20 * dx[k] + r21 * dy[k] + r22 * dz[k];

        tr[3 * k + 0] = tx; tr[3 * k + 1] = ty; tr[3 * k + 2] = tz;

        Rm[9 * k + 0] = r00; Rm[9 * k + 1] = r01; Rm[9 * k + 2] = r02;
        Rm[9 * k + 3] = r10; Rm[9 * k + 4] = r11; Rm[9 * k + 5] = r12;
        Rm[9 * k + 6] = r20; Rm[9 * k + 7] = r21; Rm[9 * k + 8] = r22;
    }

    if (full) {
        float4* p = (float4*)out + 3 * t;
        p[0] = make_float4(no[0], no[1], no[2],  no[3]);
        p[1] = make_float4(no[4], no[5], no[6],  no[7]);
        p[2] = make_float4(no[8], no[9], no[10], no[11]);

        p = (float4*)(out + 3 * N) + 3 * t;
        p[0] = make_float4(nd[0], nd[1], nd[2],  nd[3]);
        p[1] = make_float4(nd[4], nd[5], nd[6],  nd[7]);
        p[2] = make_float4(nd[8], nd[9], nd[10], nd[11]);

        p = (float4*)(out + 6 * N) + 3 * t;
        p[0] = make_float4(tr[0], tr[1], tr[2],  tr[3]);
        p[1] = make_float4(tr[4], tr[5], tr[6],  tr[7]);
        p[2] = make_float4(tr[8], tr[9], tr[10], tr[11]);

        p = (float4*)(out + 9 * N) + 9 * t;
#pragma unroll
        for (int j = 0; j < 9; ++j)
            p[j] = make_float4(Rm[4 * j + 0], Rm[4 * j + 1],
                               Rm[4 * j + 2], Rm[4 * j + 3]);
    } else {
        for (int k = 0; k < 4; ++k) {
            long long n = base + k;
            if (n >= N) break;
            for (int j = 0; j < 3; ++j) {
                out[3 * n + j]          = no[3 * k + j];
                out[3 * N + 3 * n + j]  = nd[3 * k + j];
                out[6 * N + 3 * n + j]  = tr[3 * k + j];
            }
            for (int j = 0; j < 9; ++j)
                out[9 * N + 9 * n + j] = Rm[9 * k + j];
        }
    }
}

extern "C" void kernel_launch(void* const* d_in, const int* in_sizes, int n_in,
                              void* d_out, int out_size, void* d_ws, size_t ws_size,
                              hipStream_t stream) {
    const float* params = (const float*)d_in[0];
    const int*   idx    = (const int*)d_in[1];
    const float* o      = (const float*)d_in[2];
    const float* d      = (const float*)d_in[3];
    float*       out    = (float*)d_out;
    float*       cams   = (float*)d_ws;   // size*12 floats (48 KB for size=1000)

    int size = in_sizes[0] / 6;
    long long N = (long long)in_sizes[2] / 3;

    cam_precompute<<<(size + 255) / 256, 256, 0, stream>>>(params, cams, size);

    long long nq = (N + 3) / 4;
    int blocks = (int)((nq + 255) / 256);
    cam_apply<<<blocks, 256, 0, stream>>>(idx, (const float4*)o, (const float4*)d,
                                          cams, out, nq, N);
}